// Round 2
// baseline (982.120 us; speedup 1.0000x reference)
//
#include <hip/hip_runtime.h>
#include <hip/hip_bf16.h>
#include <math.h>

#define DEV __device__ __forceinline__

constexpr int Bb   = 32;
constexpr int Nn   = 128;
constexpr int Ff   = 10;
constexpr int Dd   = 64;
constexpr int TOPK = 20;
constexpr int EXTRA= 25;
constexpr int BN   = 4096;   // B*N
constexpr int TBN  = 8192;   // 2*BN
constexpr float EPS   = 1e-5f;
constexpr float SLOPE = 0.2f;

// order-preserving float<->uint encoding for atomicMax on floats
DEV unsigned int fenc(float f){
  unsigned int b = __float_as_uint(f);
  return (b & 0x80000000u) ? ~b : (b | 0x80000000u);
}
DEV float fdec(unsigned int u){
  unsigned int b = (u & 0x80000000u) ? (u & 0x7FFFFFFFu) : ~u;
  return __uint_as_float(b);
}

// ---------------- generic zero ----------------
__global__ void k_zero(float* __restrict__ p, int n){
  int i = blockIdx.x*256 + threadIdx.x;
  if(i < n) p[i] = 0.f;
}

// ---------------- emb row norms ----------------
__global__ void k_emb_norm(const float* __restrict__ emb, float* __restrict__ norms){
  int i = blockIdx.x, d = threadIdx.x;
  float v = emb[i*Dd + d];
  float s = v*v;
  for(int o=32;o>0;o>>=1) s += __shfl_down(s, o, 64);
  if(d==0) norms[i] = fmaxf(sqrtf(s), 1e-12f);
}

// ---------------- emb cosine + top-20 per row ----------------
__global__ void k_emb_topk(const float* __restrict__ emb, const float* __restrict__ norms,
                           float* __restrict__ topv, int* __restrict__ topi){
  __shared__ float se[Dd];
  __shared__ float sc[Nn];
  __shared__ float rv[Nn];
  __shared__ int   ri[Nn];
  int i = blockIdx.x, t = threadIdx.x;
  if(t < Dd) se[t] = emb[i*Dd + t];
  __syncthreads();
  float dot = 0.f;
  for(int d=0; d<Dd; d++) dot += se[d]*emb[t*Dd + d];
  sc[t] = dot/(norms[i]*norms[t]);
  __syncthreads();
  for(int k=0; k<TOPK; k++){
    rv[t] = sc[t]; ri[t] = t; __syncthreads();
    for(int o=Nn/2; o>0; o>>=1){
      if(t < o){
        float v2 = rv[t+o]; int i2 = ri[t+o];
        if(v2 > rv[t] || (v2 == rv[t] && i2 < ri[t])){ rv[t]=v2; ri[t]=i2; }
      }
      __syncthreads();
    }
    if(t==0){
      topv[i*TOPK + k] = rv[0];
      topi[i*TOPK + k] = ri[0];
      sc[ri[0]] = -INFINITY;
    }
    __syncthreads();
  }
}

// ---------------- h = x@W1, si/sj attention logits ----------------
__global__ void k_h1(const float* __restrict__ data, const float* __restrict__ emb,
                     const float* __restrict__ W1, const float* __restrict__ ai1,
                     const float* __restrict__ aj1,
                     float* __restrict__ h, float* __restrict__ si, float* __restrict__ sj){
  int r = blockIdx.x, d = threadIdx.x;
  int node = r & (Nn-1);
  __shared__ float xr[Ff];
  if(d < Ff) xr[d] = data[r*Ff + d];
  __syncthreads();
  float hv = 0.f;
  #pragma unroll
  for(int f=0; f<Ff; f++) hv += xr[f]*W1[f*Dd + d];
  h[r*Dd + d] = hv;
  float e = emb[node*Dd + d];
  float a = hv*ai1[d] + e*ai1[Dd + d];
  float b = hv*aj1[d] + e*aj1[Dd + d];
  for(int o=32;o>0;o>>=1){ a += __shfl_down(a,o,64); b += __shfl_down(b,o,64); }
  if(d==0){ si[r] = a; sj[r] = b; }
}

// ---------------- layer-1 segment softmax + aggregation ----------------
__global__ void k_agg1(const float* __restrict__ h, const float* __restrict__ si,
                       const float* __restrict__ sj, const float* __restrict__ topv,
                       const int* __restrict__ topi, const float* __restrict__ bias1,
                       float* __restrict__ agg){
  int r = blockIdx.x, d = threadIdx.x;
  int b = r >> 7, node = r & (Nn-1);
  __shared__ float sal[TOPK];
  __shared__ int   ssrc[TOPK];
  if(d < TOPK){
    int s = b*Nn + topi[node*TOPK + d];
    float sc = si[r] + sj[s];
    sc = sc >= 0.f ? sc : SLOPE*sc;
    sal[d] = sc * topv[node*TOPK + d];
    ssrc[d] = s;
  }
  __syncthreads();
  float m = -INFINITY;
  #pragma unroll
  for(int k=0;k<TOPK;k++) m = fmaxf(m, sal[k]);
  float al[TOPK]; float ssum = 0.f;
  #pragma unroll
  for(int k=0;k<TOPK;k++){ al[k] = expf(sal[k]-m); ssum += al[k]; }
  float inv = 1.0f/fmaxf(ssum, 1e-12f);
  float acc = 0.f;
  #pragma unroll
  for(int k=0;k<TOPK;k++) acc += al[k]*inv*h[ssrc[k]*Dd + d];
  agg[r*Dd + d] = acc + bias1[d];
}

// ---------------- per-channel stats over BN rows (agg1) ----------------
__global__ void k_colstats(const float* __restrict__ x, float* __restrict__ mu, float* __restrict__ var){
  int c = blockIdx.x, t = threadIdx.x;
  float s = 0.f, s2 = 0.f;
  for(int r=t; r<BN; r+=256){ float v = x[r*Dd + c]; s += v; s2 += v*v; }
  __shared__ float ls[256], ls2[256];
  ls[t]=s; ls2[t]=s2; __syncthreads();
  for(int o=128;o>0;o>>=1){
    if(t<o){ ls[t]+=ls[t+o]; ls2[t]+=ls2[t+o]; }
    __syncthreads();
  }
  if(t==0){ float m = ls[0]/BN; mu[c]=m; var[c]=ls2[0]/BN - m*m; }
}

// ---------------- BN1 + relu -> g[0:BN] ----------------
__global__ void k_bnrelu1(const float* __restrict__ agg, const float* __restrict__ mu,
                          const float* __restrict__ var, const float* __restrict__ gamma,
                          const float* __restrict__ beta, float* __restrict__ g){
  int idx = blockIdx.x*256 + threadIdx.x;
  int c = idx & (Dd-1);
  float v = agg[idx];
  float y = gamma[c]*(v - mu[c])/sqrtf(var[c]+EPS) + beta[c];
  g[idx] = fmaxf(y, 0.f);
}

// ---------------- ef = P^T @ gcn (atomic partial sums over r-splits) ----------------
__global__ void k_ef(const float* __restrict__ P, const float* __restrict__ gcn, float* __restrict__ ef){
  __shared__ float Pt[16*65];
  __shared__ float Gt[16*65];
  int t = threadIdx.x;
  int jbase = blockIdx.x*64;
  int r0base = blockIdx.y*512;
  int tr = t >> 4, tc = t & 15;
  float acc[4][4] = {};
  for(int r0=r0base; r0<r0base+512; r0+=16){
    #pragma unroll
    for(int l=0;l<4;l++){
      int lin = t + l*256;
      int rr = lin >> 6, jc = lin & 63;
      Pt[rr*65 + jc] = P[(size_t)(r0+rr)*BN + jbase + jc];
      Gt[rr*65 + jc] = gcn[(r0+rr)*Dd + jc];
    }
    __syncthreads();
    #pragma unroll
    for(int rr=0; rr<16; rr++){
      float pa[4], gb[4];
      #pragma unroll
      for(int a=0;a<4;a++) pa[a] = Pt[rr*65 + tr*4 + a];
      #pragma unroll
      for(int b=0;b<4;b++) gb[b] = Gt[rr*65 + tc*4 + b];
      #pragma unroll
      for(int a=0;a<4;a++)
        #pragma unroll
        for(int b=0;b<4;b++) acc[a][b] += pa[a]*gb[b];
    }
    __syncthreads();
  }
  #pragma unroll
  for(int a=0;a<4;a++)
    #pragma unroll
    for(int b=0;b<4;b++)
      atomicAdd(&ef[(jbase + tr*4 + a)*Dd + tc*4 + b], acc[a][b]);
}

// ---------------- row norms of g (8192 rows) ----------------
__global__ void k_rownorm(const float* __restrict__ x, float* __restrict__ nrm){
  int r = blockIdx.x, d = threadIdx.x;
  float v = x[(size_t)r*Dd + d];
  float s = v*v;
  for(int o=32;o>0;o>>=1) s += __shfl_down(s, o, 64);
  if(d==0) nrm[r] = fmaxf(sqrtf(s), 1e-12f);
}

// ---------------- S chunk GEMM: S[r][c] = g[rbase+r] . g[c] (raw dots) ----------------
__global__ void k_sgemm(const float* __restrict__ g, int rbase, float* __restrict__ S){
  __shared__ float As[64*65];
  __shared__ float Bs[64*65];
  int t = threadIdx.x;
  int ctile = blockIdx.x*64;
  int rtile = rbase + blockIdx.y*64;
  #pragma unroll
  for(int l=0;l<16;l+=4){
    #pragma unroll
    for(int u=0;u<4;u++){
      int lin = t + (l+u)*256;
      int row = lin >> 6, d = lin & 63;
      As[row*65 + d] = g[(size_t)(rtile+row)*Dd + d];
      Bs[row*65 + d] = g[(size_t)(ctile+row)*Dd + d];
    }
  }
  __syncthreads();
  int tr = t >> 4, tc = t & 15;
  float acc[4][4] = {};
  for(int k=0;k<Dd;k++){
    float a[4], b[4];
    #pragma unroll
    for(int i=0;i<4;i++) a[i] = As[(tr*4+i)*65 + k];
    #pragma unroll
    for(int i=0;i<4;i++) b[i] = Bs[(tc*4+i)*65 + k];
    #pragma unroll
    for(int i=0;i<4;i++)
      #pragma unroll
      for(int j=0;j<4;j++) acc[i][j] += a[i]*b[j];
  }
  int rloc = blockIdx.y*64;
  #pragma unroll
  for(int i=0;i<4;i++){
    float4 v = make_float4(acc[i][0],acc[i][1],acc[i][2],acc[i][3]);
    *(float4*)&S[(size_t)(rloc + tr*4 + i)*TBN + ctile + tc*4] = v;
  }
}

// ---------------- top-25 per row of S chunk (cosine = S/(nr*nc)) ----------------
__global__ void k_top2(const float* __restrict__ S, const float* __restrict__ gnorm, int rbase,
                       float* __restrict__ topv2, int* __restrict__ topi2){
  __shared__ float row[TBN];
  __shared__ float rv[256];
  __shared__ int   ri[256];
  int r = blockIdx.x, t = threadIdx.x;
  int gr = rbase + r;
  const float* src = S + (size_t)r*TBN;
  float nr = gnorm[gr];
  for(int c=t; c<TBN; c+=256) row[c] = src[c]/(nr*gnorm[c]);
  __syncthreads();
  for(int k=0;k<EXTRA;k++){
    float bv = -INFINITY; int bi = TBN;
    for(int c=t; c<TBN; c+=256){
      float v = row[c];
      if(v > bv){ bv = v; bi = c; }
    }
    rv[t]=bv; ri[t]=bi; __syncthreads();
    for(int o=128;o>0;o>>=1){
      if(t<o){
        float v2=rv[t+o]; int i2=ri[t+o];
        if(v2>rv[t] || (v2==rv[t] && i2<ri[t])){ rv[t]=v2; ri[t]=i2; }
      }
      __syncthreads();
    }
    if(t==0){
      topv2[gr*EXTRA + k] = rv[0];
      topi2[gr*EXTRA + k] = ri[0];
      row[ri[0]] = -INFINITY;
    }
    __syncthreads();
  }
}

// ---------------- h2 = g@W2, attention logits ----------------
__global__ void k_h2(const float* __restrict__ g, const float* __restrict__ W2,
                     const float* __restrict__ ai2w, const float* __restrict__ aj2w,
                     float* __restrict__ h2, float* __restrict__ a2i, float* __restrict__ a2j){
  int r = blockIdx.x, d = threadIdx.x;
  __shared__ float gr[Dd];
  gr[d] = g[(size_t)r*Dd + d];
  __syncthreads();
  float hv = 0.f;
  #pragma unroll
  for(int k=0;k<Dd;k++) hv += gr[k]*W2[k*Dd + d];
  h2[(size_t)r*Dd + d] = hv;
  float a = hv*ai2w[d];
  float b = hv*aj2w[d];
  for(int o=32;o>0;o>>=1){ a += __shfl_down(a,o,64); b += __shfl_down(b,o,64); }
  if(d==0){ a2i[r]=a; a2j[r]=b; }
}

// ---------------- layer-2 edge scores + segment max ----------------
__global__ void k_s2(const float* __restrict__ a2i, const float* __restrict__ a2j,
                     const float* __restrict__ topv2, const int* __restrict__ topi2,
                     float* __restrict__ s2, unsigned int* __restrict__ segmax){
  int e = blockIdx.x*256 + threadIdx.x;
  if(e >= BN*EXTRA) return;
  int r = e/EXTRA;
  int dst = topi2[e];
  float sc = a2i[dst] + a2j[r];
  sc = sc >= 0.f ? sc : SLOPE*sc;
  sc *= topv2[e];
  s2[e] = sc;
  atomicMax(&segmax[dst], fenc(sc));
}

// ---------------- exp + segment sum ----------------
__global__ void k_e2(const float* __restrict__ s2, const int* __restrict__ topi2,
                     const unsigned int* __restrict__ segmax,
                     float* __restrict__ e2, float* __restrict__ ssum){
  int e = blockIdx.x*256 + threadIdx.x;
  if(e >= BN*EXTRA) return;
  int dst = topi2[e];
  float m = fdec(segmax[dst]);
  float v = expf(s2[e] - m);
  e2[e] = v;
  atomicAdd(&ssum[dst], v);
}

// ---------------- weighted scatter into agg2 ----------------
__global__ void k_scat(const float* __restrict__ e2, const float* __restrict__ ssum,
                       const int* __restrict__ topi2, const float* __restrict__ h2,
                       float* __restrict__ agg2){
  int idx = blockIdx.x*256 + threadIdx.x;
  int e = idx >> 6, d = idx & 63;
  int dst = topi2[e];
  int src = e/EXTRA;
  float alpha = e2[e]/fmaxf(ssum[dst], 1e-12f);
  atomicAdd(&agg2[(size_t)dst*Dd + d], alpha*h2[(size_t)src*Dd + d]);
}

// ---------------- head stats over x3 = relu(agg2+bias2)*emb ----------------
__global__ void k_headstats(const float* __restrict__ agg2, const float* __restrict__ bias2,
                            const float* __restrict__ emb, float* __restrict__ mu2, float* __restrict__ var2){
  int c = blockIdx.x, t = threadIdx.x;
  float bc = bias2[c];
  float s = 0.f, s2 = 0.f;
  for(int r=t; r<BN; r+=256){
    float v = fmaxf(agg2[(size_t)r*Dd + c] + bc, 0.f) * emb[(r & (Nn-1))*Dd + c];
    s += v; s2 += v*v;
  }
  __shared__ float ls[256], ls2[256];
  ls[t]=s; ls2[t]=s2; __syncthreads();
  for(int o=128;o>0;o>>=1){
    if(t<o){ ls[t]+=ls[t+o]; ls2[t]+=ls2[t+o]; }
    __syncthreads();
  }
  if(t==0){ float m=ls[0]/BN; mu2[c]=m; var2[c]=ls2[0]/BN - m*m; }
}

// ---------------- final: BN + relu + Linear(D,1) ----------------
__global__ void k_out(const float* __restrict__ agg2, const float* __restrict__ bias2,
                      const float* __restrict__ emb, const float* __restrict__ mu2,
                      const float* __restrict__ var2, const float* __restrict__ gO,
                      const float* __restrict__ bO, const float* __restrict__ Wout,
                      const float* __restrict__ bout, float* __restrict__ out){
  int r = blockIdx.x, d = threadIdx.x;
  float v = fmaxf(agg2[(size_t)r*Dd + d] + bias2[d], 0.f) * emb[(r & (Nn-1))*Dd + d];
  float y = gO[d]*(v - mu2[d])/sqrtf(var2[d]+EPS) + bO[d];
  y = fmaxf(y, 0.f)*Wout[d];
  for(int o=32;o>0;o>>=1) y += __shfl_down(y, o, 64);
  if(d==0) out[r] = y + bout[0];
}

extern "C" void kernel_launch(void* const* d_in, const int* in_sizes, int n_in,
                              void* d_out, int out_size, void* d_ws, size_t ws_size,
                              hipStream_t stream){
  const float* data  = (const float*)d_in[0];
  const float* emb   = (const float*)d_in[1];
  const float* W1    = (const float*)d_in[2];
  const float* ai1   = (const float*)d_in[3];
  const float* aj1   = (const float*)d_in[4];
  const float* bias1 = (const float*)d_in[5];
  const float* bn1g  = (const float*)d_in[6];
  const float* bn1b  = (const float*)d_in[7];
  const float* P     = (const float*)d_in[8];
  const float* W2    = (const float*)d_in[9];
  const float* ai2w  = (const float*)d_in[10];
  const float* aj2w  = (const float*)d_in[11];
  const float* bias2 = (const float*)d_in[12];
  const float* bnOg  = (const float*)d_in[13];
  const float* bnOb  = (const float*)d_in[14];
  const float* Wout  = (const float*)d_in[15];
  const float* bout  = (const float*)d_in[16];
  float* out = (float*)d_out;

  char* w = (char*)d_ws;
  auto alloc = [&](size_t nbytes)->char*{
    char* p = w; w += (nbytes + 255) & ~(size_t)255; return p;
  };
  float* norms1 = (float*)alloc(Nn*4);
  float* topv1  = (float*)alloc(Nn*TOPK*4);
  int*   topi1  = (int*)  alloc(Nn*TOPK*4);
  float* h      = (float*)alloc((size_t)BN*Dd*4);
  float* si     = (float*)alloc(BN*4);
  float* sj     = (float*)alloc(BN*4);
  float* agg1   = (float*)alloc((size_t)BN*Dd*4);
  float* mu1    = (float*)alloc(Dd*4);
  float* var1   = (float*)alloc(Dd*4);
  float* g      = (float*)alloc((size_t)TBN*Dd*4);
  float* gnorm  = (float*)alloc(TBN*4);
  float* topv2  = (float*)alloc((size_t)BN*EXTRA*4);
  int*   topi2  = (int*)  alloc((size_t)BN*EXTRA*4);
  float* h2     = (float*)alloc((size_t)TBN*Dd*4);
  float* a2i    = (float*)alloc(TBN*4);
  float* a2j    = (float*)alloc(TBN*4);
  float* s2     = (float*)alloc((size_t)BN*EXTRA*4);
  float* e2     = (float*)alloc((size_t)BN*EXTRA*4);
  unsigned int* segmax = (unsigned int*)alloc(TBN*4);
  float* ssum   = (float*)alloc(TBN*4);
  float* agg2   = (float*)alloc((size_t)TBN*Dd*4);
  float* mu2    = (float*)alloc(Dd*4);
  float* var2   = (float*)alloc(Dd*4);

  // adaptive S-chunk: as many 64-row slabs of [rows x TBN] fp32 as ws allows (max 512 rows)
  size_t used = (size_t)(w - (char*)d_ws);
  size_t rem  = ws_size > used ? ws_size - used : 0;
  int chunkRows = 512;
  while(chunkRows > 64 && (size_t)chunkRows*TBN*4 > rem) chunkRows >>= 1;
  float* Schunk = (float*)alloc((size_t)chunkRows*TBN*4);

  // ---- layer 1 ----
  k_emb_norm<<<Nn, 64, 0, stream>>>(emb, norms1);
  k_emb_topk<<<Nn, Nn, 0, stream>>>(emb, norms1, topv1, topi1);
  k_h1<<<BN, 64, 0, stream>>>(data, emb, W1, ai1, aj1, h, si, sj);
  k_agg1<<<BN, 64, 0, stream>>>(h, si, sj, topv1, topi1, bias1, agg1);
  k_colstats<<<Dd, 256, 0, stream>>>(agg1, mu1, var1);
  k_bnrelu1<<<(BN*Dd)/256, 256, 0, stream>>>(agg1, mu1, var1, bn1g, bn1b, g);

  // ---- ef = P^T gcn ----
  k_zero<<<(BN*Dd)/256, 256, 0, stream>>>(g + (size_t)BN*Dd, BN*Dd);
  k_ef<<<dim3(64, 8), 256, 0, stream>>>(P, g, g + (size_t)BN*Dd);

  // ---- cos2 top-25 (chunked; only first BN rows are consumed downstream) ----
  k_rownorm<<<TBN, 64, 0, stream>>>(g, gnorm);
  for(int rbase=0; rbase<BN; rbase+=chunkRows){
    k_sgemm<<<dim3(TBN/64, chunkRows/64), 256, 0, stream>>>(g, rbase, Schunk);
    k_top2<<<chunkRows, 256, 0, stream>>>(Schunk, gnorm, rbase, topv2, topi2);
  }

  // ---- layer 2 ----
  k_h2<<<TBN, 64, 0, stream>>>(g, W2, ai2w, aj2w, h2, a2i, a2j);
  k_zero<<<(TBN*Dd)/256, 256, 0, stream>>>(agg2, TBN*Dd);
  k_zero<<<TBN/256, 256, 0, stream>>>(ssum, TBN);
  k_zero<<<TBN/256, 256, 0, stream>>>((float*)segmax, TBN);
  k_s2<<<(BN*EXTRA + 255)/256, 256, 0, stream>>>(a2i, a2j, topv2, topi2, s2, segmax);
  k_e2<<<(BN*EXTRA + 255)/256, 256, 0, stream>>>(s2, topi2, segmax, e2, ssum);
  k_scat<<<(BN*EXTRA*Dd)/256, 256, 0, stream>>>(e2, ssum, topi2, h2, agg2);

  // ---- head ----
  k_headstats<<<Dd, 256, 0, stream>>>(agg2, bias2, emb, mu2, var2);
  k_out<<<BN, 64, 0, stream>>>(agg2, bias2, emb, mu2, var2, bnOg, bnOb, Wout, bout, out);
}

// Round 3
// 532.218 us; speedup vs baseline: 1.8453x; 1.8453x over previous
//
#include <hip/hip_runtime.h>
#include <hip/hip_bf16.h>
#include <math.h>

#define DEV __device__ __forceinline__

constexpr int Bb   = 32;
constexpr int Nn   = 128;
constexpr int Ff   = 10;
constexpr int Dd   = 64;
constexpr int TOPK = 20;
constexpr int EXTRA= 25;
constexpr int BN   = 4096;   // B*N
constexpr int TBN  = 8192;   // 2*BN
constexpr float EPS   = 1e-5f;
constexpr float SLOPE = 0.2f;

// order-preserving float<->uint encoding for atomicMax on floats
DEV unsigned int fenc(float f){
  unsigned int b = __float_as_uint(f);
  return (b & 0x80000000u) ? ~b : (b | 0x80000000u);
}
DEV float fdec(unsigned int u){
  unsigned int b = (u & 0x80000000u) ? (u & 0x7FFFFFFFu) : ~u;
  return __uint_as_float(b);
}

// ---------------- generic zero ----------------
__global__ void k_zero(float* __restrict__ p, int n){
  int i = blockIdx.x*256 + threadIdx.x;
  if(i < n) p[i] = 0.f;
}

// ---------------- emb row norms ----------------
__global__ void k_emb_norm(const float* __restrict__ emb, float* __restrict__ norms){
  int i = blockIdx.x, d = threadIdx.x;
  float v = emb[i*Dd + d];
  float s = v*v;
  for(int o=32;o>0;o>>=1) s += __shfl_down(s, o, 64);
  if(d==0) norms[i] = fmaxf(sqrtf(s), 1e-12f);
}

// ---------------- emb cosine + top-20 per row ----------------
__global__ void k_emb_topk(const float* __restrict__ emb, const float* __restrict__ norms,
                           float* __restrict__ topv, int* __restrict__ topi){
  __shared__ float se[Dd];
  __shared__ float sc[Nn];
  __shared__ float rv[Nn];
  __shared__ int   ri[Nn];
  int i = blockIdx.x, t = threadIdx.x;
  if(t < Dd) se[t] = emb[i*Dd + t];
  __syncthreads();
  float dot = 0.f;
  for(int d=0; d<Dd; d++) dot += se[d]*emb[t*Dd + d];
  sc[t] = dot/(norms[i]*norms[t]);
  __syncthreads();
  for(int k=0; k<TOPK; k++){
    rv[t] = sc[t]; ri[t] = t; __syncthreads();
    for(int o=Nn/2; o>0; o>>=1){
      if(t < o){
        float v2 = rv[t+o]; int i2 = ri[t+o];
        if(v2 > rv[t] || (v2 == rv[t] && i2 < ri[t])){ rv[t]=v2; ri[t]=i2; }
      }
      __syncthreads();
    }
    if(t==0){
      topv[i*TOPK + k] = rv[0];
      topi[i*TOPK + k] = ri[0];
      sc[ri[0]] = -INFINITY;
    }
    __syncthreads();
  }
}

// ---------------- h = x@W1, si/sj attention logits ----------------
__global__ void k_h1(const float* __restrict__ data, const float* __restrict__ emb,
                     const float* __restrict__ W1, const float* __restrict__ ai1,
                     const float* __restrict__ aj1,
                     float* __restrict__ h, float* __restrict__ si, float* __restrict__ sj){
  int r = blockIdx.x, d = threadIdx.x;
  int node = r & (Nn-1);
  __shared__ float xr[Ff];
  if(d < Ff) xr[d] = data[r*Ff + d];
  __syncthreads();
  float hv = 0.f;
  #pragma unroll
  for(int f=0; f<Ff; f++) hv += xr[f]*W1[f*Dd + d];
  h[r*Dd + d] = hv;
  float e = emb[node*Dd + d];
  float a = hv*ai1[d] + e*ai1[Dd + d];
  float b = hv*aj1[d] + e*aj1[Dd + d];
  for(int o=32;o>0;o>>=1){ a += __shfl_down(a,o,64); b += __shfl_down(b,o,64); }
  if(d==0){ si[r] = a; sj[r] = b; }
}

// ---------------- layer-1 segment softmax + aggregation ----------------
__global__ void k_agg1(const float* __restrict__ h, const float* __restrict__ si,
                       const float* __restrict__ sj, const float* __restrict__ topv,
                       const int* __restrict__ topi, const float* __restrict__ bias1,
                       float* __restrict__ agg){
  int r = blockIdx.x, d = threadIdx.x;
  int b = r >> 7, node = r & (Nn-1);
  __shared__ float sal[TOPK];
  __shared__ int   ssrc[TOPK];
  if(d < TOPK){
    int s = b*Nn + topi[node*TOPK + d];
    float sc = si[r] + sj[s];
    sc = sc >= 0.f ? sc : SLOPE*sc;
    sal[d] = sc * topv[node*TOPK + d];
    ssrc[d] = s;
  }
  __syncthreads();
  float m = -INFINITY;
  #pragma unroll
  for(int k=0;k<TOPK;k++) m = fmaxf(m, sal[k]);
  float al[TOPK]; float ssum = 0.f;
  #pragma unroll
  for(int k=0;k<TOPK;k++){ al[k] = expf(sal[k]-m); ssum += al[k]; }
  float inv = 1.0f/fmaxf(ssum, 1e-12f);
  float acc = 0.f;
  #pragma unroll
  for(int k=0;k<TOPK;k++) acc += al[k]*inv*h[ssrc[k]*Dd + d];
  agg[r*Dd + d] = acc + bias1[d];
}

// ---------------- per-channel stats over BN rows (agg1) ----------------
__global__ void k_colstats(const float* __restrict__ x, float* __restrict__ mu, float* __restrict__ var){
  int c = blockIdx.x, t = threadIdx.x;
  float s = 0.f, s2 = 0.f;
  for(int r=t; r<BN; r+=256){ float v = x[r*Dd + c]; s += v; s2 += v*v; }
  __shared__ float ls[256], ls2[256];
  ls[t]=s; ls2[t]=s2; __syncthreads();
  for(int o=128;o>0;o>>=1){
    if(t<o){ ls[t]+=ls[t+o]; ls2[t]+=ls2[t+o]; }
    __syncthreads();
  }
  if(t==0){ float m = ls[0]/BN; mu[c]=m; var[c]=ls2[0]/BN - m*m; }
}

// ---------------- BN1 + relu -> g[0:BN] ----------------
__global__ void k_bnrelu1(const float* __restrict__ agg, const float* __restrict__ mu,
                          const float* __restrict__ var, const float* __restrict__ gamma,
                          const float* __restrict__ beta, float* __restrict__ g){
  int idx = blockIdx.x*256 + threadIdx.x;
  int c = idx & (Dd-1);
  float v = agg[idx];
  float y = gamma[c]*(v - mu[c])/sqrtf(var[c]+EPS) + beta[c];
  g[idx] = fmaxf(y, 0.f);
}

// ---------------- ef = P^T @ gcn : float4 staging, grid (64 j-tiles, 16 r-chunks) ----------------
__global__ __launch_bounds__(256) void k_ef(const float* __restrict__ P, const float* __restrict__ gcn,
                                            float* __restrict__ ef){
  __shared__ float Pt[16*64];
  __shared__ float Gt[16*64];
  int t = threadIdx.x;
  int jbase = blockIdx.x*64;
  int r0 = blockIdx.y*256;
  int row = t >> 4, col4 = (t & 15)*4;
  int tr = t >> 4, tc = t & 15;
  float acc[4][4] = {};
  for(int step=0; step<16; step++){
    int r = r0 + step*16;
    float4 pv = *(const float4*)&P[(size_t)(r+row)*BN + jbase + col4];
    float4 gv = *(const float4*)&gcn[(r+row)*Dd + col4];
    __syncthreads();
    *(float4*)&Pt[row*64 + col4] = pv;
    *(float4*)&Gt[row*64 + col4] = gv;
    __syncthreads();
    #pragma unroll
    for(int rr=0; rr<16; rr++){
      float4 pa = *(float4*)&Pt[rr*64 + tr*4];
      float4 gb = *(float4*)&Gt[rr*64 + tc*4];
      float pav[4] = {pa.x, pa.y, pa.z, pa.w};
      float gbv[4] = {gb.x, gb.y, gb.z, gb.w};
      #pragma unroll
      for(int a=0;a<4;a++)
        #pragma unroll
        for(int b=0;b<4;b++) acc[a][b] += pav[a]*gbv[b];
    }
  }
  #pragma unroll
  for(int a=0;a<4;a++)
    #pragma unroll
    for(int b=0;b<4;b++)
      atomicAdd(&ef[(jbase + tr*4 + a)*Dd + tc*4 + b], acc[a][b]);
}

// ---------------- row norms of g (8192 rows) ----------------
__global__ void k_rownorm(const float* __restrict__ x, float* __restrict__ nrm){
  int r = blockIdx.x, d = threadIdx.x;
  float v = x[(size_t)r*Dd + d];
  float s = v*v;
  for(int o=32;o>0;o>>=1) s += __shfl_down(s, o, 64);
  if(d==0) nrm[r] = fmaxf(sqrtf(s), 1e-12f);
}

// ---------------- S chunk GEMM: S[r][c] = cos(g[rbase+r], g[c]) ----------------
// 128x128 tile, 256 threads, 8x8 acc, LDS layout [k][m] (transposed), norm folded into staging.
__global__ __launch_bounds__(256) void k_sgemm(const float* __restrict__ g, const float* __restrict__ gnorm,
                                               int rbase, float* __restrict__ S){
  __shared__ float A[64*128];
  __shared__ float Bs[64*128];
  int t = threadIdx.x;
  int ctile = blockIdx.x*128;
  int rtile = rbase + blockIdx.y*128;
  int q = t >> 4, m0 = t & 15;          // q: k4 group (0..15), m0: row (0..15)
  #pragma unroll
  for(int l=0;l<8;l++){
    int m = m0 + 16*l;
    float ia = 1.0f/gnorm[rtile + m];
    float ib = 1.0f/gnorm[ctile + m];
    float4 av = *(const float4*)&g[(size_t)(rtile+m)*Dd + q*4];
    float4 bv = *(const float4*)&g[(size_t)(ctile+m)*Dd + q*4];
    A[(q*4+0)*128 + m] = av.x*ia; A[(q*4+1)*128 + m] = av.y*ia;
    A[(q*4+2)*128 + m] = av.z*ia; A[(q*4+3)*128 + m] = av.w*ia;
    Bs[(q*4+0)*128 + m] = bv.x*ib; Bs[(q*4+1)*128 + m] = bv.y*ib;
    Bs[(q*4+2)*128 + m] = bv.z*ib; Bs[(q*4+3)*128 + m] = bv.w*ib;
  }
  __syncthreads();
  int tr = t >> 4;   // m-group (broadcast within wave)
  int tc = t & 15;   // n-group (fast index -> semi-coalesced stores)
  float acc[8][8] = {};
  #pragma unroll 4
  for(int k=0;k<64;k++){
    float a[8], b[8];
    #pragma unroll
    for(int i=0;i<8;i++) a[i] = A[k*128 + tr + 16*i];
    #pragma unroll
    for(int j=0;j<8;j++) b[j] = Bs[k*128 + tc + 16*j];
    #pragma unroll
    for(int i=0;i<8;i++)
      #pragma unroll
      for(int j=0;j<8;j++) acc[i][j] += a[i]*b[j];
  }
  int rloc = blockIdx.y*128;
  #pragma unroll
  for(int i=0;i<8;i++){
    int r = rloc + tr + 16*i;
    #pragma unroll
    for(int j=0;j<8;j++)
      S[(size_t)r*TBN + ctile + tc + 16*j] = acc[i][j];
  }
}

// ---------------- top-25 per row: incremental argmax selection ----------------
__global__ __launch_bounds__(256) void k_top2(const float* __restrict__ S, int rbase,
                                              float* __restrict__ topv2, int* __restrict__ topi2){
  __shared__ float row[TBN];
  __shared__ float wv[4];
  __shared__ int   wi[4];
  int t = threadIdx.x;
  int r = blockIdx.x;
  const float* src = S + (size_t)r*TBN;
  float mv = -INFINITY; int mi = 0x7FFFFFFF;
  #pragma unroll
  for(int i=0;i<8;i++){
    int c = i*1024 + t*4;
    float4 v = *(const float4*)&src[c];
    *(float4*)&row[c] = v;
    if(v.x > mv){mv=v.x;mi=c;}
    if(v.y > mv){mv=v.y;mi=c+1;}
    if(v.z > mv){mv=v.z;mi=c+2;}
    if(v.w > mv){mv=v.w;mi=c+3;}
  }
  __syncthreads();
  int gr = rbase + r;
  int lane = t & 63, wid = t >> 6;
  for(int k=0;k<EXTRA;k++){
    float v = mv; int i = mi;
    for(int o=32;o;o>>=1){
      float v2 = __shfl_down(v,o,64); int i2 = __shfl_down(i,o,64);
      if(v2 > v || (v2 == v && i2 < i)){ v=v2; i=i2; }
    }
    if(lane==0){ wv[wid]=v; wi[wid]=i; }
    __syncthreads();
    float gv = wv[0]; int gi = wi[0];
    #pragma unroll
    for(int w2=1; w2<4; w2++){
      float vv = wv[w2]; int ii = wi[w2];
      if(vv > gv || (vv == gv && ii < gi)){ gv=vv; gi=ii; }
    }
    if(t==0){ topv2[gr*EXTRA+k]=gv; topi2[gr*EXTRA+k]=gi; }
    int owner = (gi & 1023) >> 2;
    if(t == owner){
      row[gi] = -INFINITY;
      mv = -INFINITY; mi = 0x7FFFFFFF;
      #pragma unroll
      for(int i2=0;i2<8;i2++){
        int c = i2*1024 + t*4;
        float4 vv = *(float4*)&row[c];
        if(vv.x > mv){mv=vv.x;mi=c;}
        if(vv.y > mv){mv=vv.y;mi=c+1;}
        if(vv.z > mv){mv=vv.z;mi=c+2;}
        if(vv.w > mv){mv=vv.w;mi=c+3;}
      }
    }
    __syncthreads();
  }
}

// ---------------- h2 = g@W2, attention logits ----------------
__global__ void k_h2(const float* __restrict__ g, const float* __restrict__ W2,
                     const float* __restrict__ ai2w, const float* __restrict__ aj2w,
                     float* __restrict__ h2, float* __restrict__ a2i, float* __restrict__ a2j){
  int r = blockIdx.x, d = threadIdx.x;
  __shared__ float gr[Dd];
  gr[d] = g[(size_t)r*Dd + d];
  __syncthreads();
  float hv = 0.f;
  #pragma unroll
  for(int k=0;k<Dd;k++) hv += gr[k]*W2[k*Dd + d];
  h2[(size_t)r*Dd + d] = hv;
  float a = hv*ai2w[d];
  float b = hv*aj2w[d];
  for(int o=32;o>0;o>>=1){ a += __shfl_down(a,o,64); b += __shfl_down(b,o,64); }
  if(d==0){ a2i[r]=a; a2j[r]=b; }
}

// ---------------- layer-2 edge scores + segment max ----------------
__global__ void k_s2(const float* __restrict__ a2i, const float* __restrict__ a2j,
                     const float* __restrict__ topv2, const int* __restrict__ topi2,
                     float* __restrict__ s2, unsigned int* __restrict__ segmax){
  int e = blockIdx.x*256 + threadIdx.x;
  if(e >= BN*EXTRA) return;
  int r = e/EXTRA;
  int dst = topi2[e];
  float sc = a2i[dst] + a2j[r];
  sc = sc >= 0.f ? sc : SLOPE*sc;
  sc *= topv2[e];
  s2[e] = sc;
  atomicMax(&segmax[dst], fenc(sc));
}

// ---------------- exp + segment sum ----------------
__global__ void k_e2(const float* __restrict__ s2, const int* __restrict__ topi2,
                     const unsigned int* __restrict__ segmax,
                     float* __restrict__ e2, float* __restrict__ ssum){
  int e = blockIdx.x*256 + threadIdx.x;
  if(e >= BN*EXTRA) return;
  int dst = topi2[e];
  float m = fdec(segmax[dst]);
  float v = expf(s2[e] - m);
  e2[e] = v;
  atomicAdd(&ssum[dst], v);
}

// ---------------- weighted scatter into agg2 ----------------
__global__ void k_scat(const float* __restrict__ e2, const float* __restrict__ ssum,
                       const int* __restrict__ topi2, const float* __restrict__ h2,
                       float* __restrict__ agg2){
  int idx = blockIdx.x*256 + threadIdx.x;
  int e = idx >> 6, d = idx & 63;
  int dst = topi2[e];
  int src = e/EXTRA;
  float alpha = e2[e]/fmaxf(ssum[dst], 1e-12f);
  atomicAdd(&agg2[(size_t)dst*Dd + d], alpha*h2[(size_t)src*Dd + d]);
}

// ---------------- head stats over x3 = relu(agg2+bias2)*emb ----------------
__global__ void k_headstats(const float* __restrict__ agg2, const float* __restrict__ bias2,
                            const float* __restrict__ emb, float* __restrict__ mu2, float* __restrict__ var2){
  int c = blockIdx.x, t = threadIdx.x;
  float bc = bias2[c];
  float s = 0.f, s2 = 0.f;
  for(int r=t; r<BN; r+=256){
    float v = fmaxf(agg2[(size_t)r*Dd + c] + bc, 0.f) * emb[(r & (Nn-1))*Dd + c];
    s += v; s2 += v*v;
  }
  __shared__ float ls[256], ls2[256];
  ls[t]=s; ls2[t]=s2; __syncthreads();
  for(int o=128;o>0;o>>=1){
    if(t<o){ ls[t]+=ls[t+o]; ls2[t]+=ls2[t+o]; }
    __syncthreads();
  }
  if(t==0){ float m=ls[0]/BN; mu2[c]=m; var2[c]=ls2[0]/BN - m*m; }
}

// ---------------- final: BN + relu + Linear(D,1) ----------------
__global__ void k_out(const float* __restrict__ agg2, const float* __restrict__ bias2,
                      const float* __restrict__ emb, const float* __restrict__ mu2,
                      const float* __restrict__ var2, const float* __restrict__ gO,
                      const float* __restrict__ bO, const float* __restrict__ Wout,
                      const float* __restrict__ bout, float* __restrict__ out){
  int r = blockIdx.x, d = threadIdx.x;
  float v = fmaxf(agg2[(size_t)r*Dd + d] + bias2[d], 0.f) * emb[(r & (Nn-1))*Dd + d];
  float y = gO[d]*(v - mu2[d])/sqrtf(var2[d]+EPS) + bO[d];
  y = fmaxf(y, 0.f)*Wout[d];
  for(int o=32;o>0;o>>=1) y += __shfl_down(y, o, 64);
  if(d==0) out[r] = y + bout[0];
}

extern "C" void kernel_launch(void* const* d_in, const int* in_sizes, int n_in,
                              void* d_out, int out_size, void* d_ws, size_t ws_size,
                              hipStream_t stream){
  const float* data  = (const float*)d_in[0];
  const float* emb   = (const float*)d_in[1];
  const float* W1    = (const float*)d_in[2];
  const float* ai1   = (const float*)d_in[3];
  const float* aj1   = (const float*)d_in[4];
  const float* bias1 = (const float*)d_in[5];
  const float* bn1g  = (const float*)d_in[6];
  const float* bn1b  = (const float*)d_in[7];
  const float* P     = (const float*)d_in[8];
  const float* W2    = (const float*)d_in[9];
  const float* ai2w  = (const float*)d_in[10];
  const float* aj2w  = (const float*)d_in[11];
  const float* bias2 = (const float*)d_in[12];
  const float* bnOg  = (const float*)d_in[13];
  const float* bnOb  = (const float*)d_in[14];
  const float* Wout  = (const float*)d_in[15];
  const float* bout  = (const float*)d_in[16];
  float* out = (float*)d_out;

  char* w = (char*)d_ws;
  auto alloc = [&](size_t nbytes)->char*{
    char* p = w; w += (nbytes + 255) & ~(size_t)255; return p;
  };
  float* norms1 = (float*)alloc(Nn*4);
  float* topv1  = (float*)alloc(Nn*TOPK*4);
  int*   topi1  = (int*)  alloc(Nn*TOPK*4);
  float* h      = (float*)alloc((size_t)BN*Dd*4);
  float* si     = (float*)alloc(BN*4);
  float* sj     = (float*)alloc(BN*4);
  float* agg1   = (float*)alloc((size_t)BN*Dd*4);
  float* mu1    = (float*)alloc(Dd*4);
  float* var1   = (float*)alloc(Dd*4);
  float* g      = (float*)alloc((size_t)TBN*Dd*4);
  float* gnorm  = (float*)alloc(TBN*4);
  float* topv2  = (float*)alloc((size_t)BN*EXTRA*4);
  int*   topi2  = (int*)  alloc((size_t)BN*EXTRA*4);
  float* h2     = (float*)alloc((size_t)TBN*Dd*4);
  float* a2i    = (float*)alloc(TBN*4);
  float* a2j    = (float*)alloc(TBN*4);
  float* s2     = (float*)alloc((size_t)BN*EXTRA*4);
  float* e2     = (float*)alloc((size_t)BN*EXTRA*4);
  // contiguous zero region: agg2 | ssum | segmax
  float* zblock = (float*)alloc(((size_t)TBN*Dd + TBN + TBN)*4);
  float* agg2   = zblock;
  float* ssum   = zblock + (size_t)TBN*Dd;
  unsigned int* segmax = (unsigned int*)(ssum + TBN);
  float* mu2    = (float*)alloc(Dd*4);
  float* var2   = (float*)alloc(Dd*4);

  // adaptive S-chunk (multiple of 128 rows; prefer fewer, larger chunks)
  size_t used = (size_t)(w - (char*)d_ws);
  size_t rem  = ws_size > used ? ws_size - used : 0;
  int chunkRows = 2048;
  while(chunkRows > 128 && (size_t)chunkRows*TBN*4 > rem) chunkRows >>= 1;
  float* Schunk = (float*)alloc((size_t)chunkRows*TBN*4);

  // ---- layer 1 ----
  k_emb_norm<<<Nn, 64, 0, stream>>>(emb, norms1);
  k_emb_topk<<<Nn, Nn, 0, stream>>>(emb, norms1, topv1, topi1);
  k_h1<<<BN, 64, 0, stream>>>(data, emb, W1, ai1, aj1, h, si, sj);
  k_agg1<<<BN, 64, 0, stream>>>(h, si, sj, topv1, topi1, bias1, agg1);
  k_colstats<<<Dd, 256, 0, stream>>>(agg1, mu1, var1);
  k_bnrelu1<<<(BN*Dd)/256, 256, 0, stream>>>(agg1, mu1, var1, bn1g, bn1b, g);

  // ---- ef = P^T gcn ----
  k_zero<<<(BN*Dd)/256, 256, 0, stream>>>(g + (size_t)BN*Dd, BN*Dd);
  k_ef<<<dim3(64, 16), 256, 0, stream>>>(P, g, g + (size_t)BN*Dd);

  // ---- cos2 top-25 (chunked; only first BN rows consumed downstream) ----
  k_rownorm<<<TBN, 64, 0, stream>>>(g, gnorm);
  for(int rbase=0; rbase<BN; rbase+=chunkRows){
    k_sgemm<<<dim3(TBN/128, chunkRows/128), 256, 0, stream>>>(g, gnorm, rbase, Schunk);
    k_top2<<<chunkRows, 256, 0, stream>>>(Schunk, rbase, topv2, topi2);
  }

  // ---- layer 2 ----
  k_h2<<<TBN, 64, 0, stream>>>(g, W2, ai2w, aj2w, h2, a2i, a2j);
  k_zero<<<((TBN*Dd + 2*TBN) + 255)/256, 256, 0, stream>>>(zblock, TBN*Dd + 2*TBN);
  k_s2<<<(BN*EXTRA + 255)/256, 256, 0, stream>>>(a2i, a2j, topv2, topi2, s2, segmax);
  k_e2<<<(BN*EXTRA + 255)/256, 256, 0, stream>>>(s2, topi2, segmax, e2, ssum);
  k_scat<<<(BN*EXTRA*Dd)/256, 256, 0, stream>>>(e2, ssum, topi2, h2, agg2);

  // ---- head ----
  k_headstats<<<Dd, 256, 0, stream>>>(agg2, bias2, emb, mu2, var2);
  k_out<<<BN, 64, 0, stream>>>(agg2, bias2, emb, mu2, var2, bnOg, bnOb, Wout, bout, out);
}

// Round 4
// 500.328 us; speedup vs baseline: 1.9630x; 1.0637x over previous
//
#include <hip/hip_runtime.h>
#include <hip/hip_bf16.h>
#include <math.h>

#define DEV __device__ __forceinline__

constexpr int Bb   = 32;
constexpr int Nn   = 128;
constexpr int Ff   = 10;
constexpr int Dd   = 64;
constexpr int TOPK = 20;
constexpr int EXTRA= 25;
constexpr int BN   = 4096;   // B*N
constexpr int TBN  = 8192;   // 2*BN
constexpr float EPS   = 1e-5f;
constexpr float SLOPE = 0.2f;

// order-preserving float<->uint encoding for atomicMax on floats
DEV unsigned int fenc(float f){
  unsigned int b = __float_as_uint(f);
  return (b & 0x80000000u) ? ~b : (b | 0x80000000u);
}
DEV float fdec(unsigned int u){
  unsigned int b = (u & 0x80000000u) ? (u & 0x7FFFFFFFu) : ~u;
  return __uint_as_float(b);
}

// ---------------- generic zero ----------------
__global__ void k_zero(float* __restrict__ p, int n){
  int i = blockIdx.x*256 + threadIdx.x;
  if(i < n) p[i] = 0.f;
}

// ---------------- emb row norms ----------------
__global__ void k_emb_norm(const float* __restrict__ emb, float* __restrict__ norms){
  int i = blockIdx.x, d = threadIdx.x;
  float v = emb[i*Dd + d];
  float s = v*v;
  for(int o=32;o>0;o>>=1) s += __shfl_down(s, o, 64);
  if(d==0) norms[i] = fmaxf(sqrtf(s), 1e-12f);
}

// ---------------- emb cosine + top-20 per row ----------------
__global__ void k_emb_topk(const float* __restrict__ emb, const float* __restrict__ norms,
                           float* __restrict__ topv, int* __restrict__ topi){
  __shared__ float se[Dd];
  __shared__ float sc[Nn];
  __shared__ float rv[Nn];
  __shared__ int   ri[Nn];
  int i = blockIdx.x, t = threadIdx.x;
  if(t < Dd) se[t] = emb[i*Dd + t];
  __syncthreads();
  float dot = 0.f;
  for(int d=0; d<Dd; d++) dot += se[d]*emb[t*Dd + d];
  sc[t] = dot/(norms[i]*norms[t]);
  __syncthreads();
  for(int k=0; k<TOPK; k++){
    rv[t] = sc[t]; ri[t] = t; __syncthreads();
    for(int o=Nn/2; o>0; o>>=1){
      if(t < o){
        float v2 = rv[t+o]; int i2 = ri[t+o];
        if(v2 > rv[t] || (v2 == rv[t] && i2 < ri[t])){ rv[t]=v2; ri[t]=i2; }
      }
      __syncthreads();
    }
    if(t==0){
      topv[i*TOPK + k] = rv[0];
      topi[i*TOPK + k] = ri[0];
      sc[ri[0]] = -INFINITY;
    }
    __syncthreads();
  }
}

// ---------------- h = x@W1, si/sj attention logits ----------------
__global__ void k_h1(const float* __restrict__ data, const float* __restrict__ emb,
                     const float* __restrict__ W1, const float* __restrict__ ai1,
                     const float* __restrict__ aj1,
                     float* __restrict__ h, float* __restrict__ si, float* __restrict__ sj){
  int r = blockIdx.x, d = threadIdx.x;
  int node = r & (Nn-1);
  __shared__ float xr[Ff];
  if(d < Ff) xr[d] = data[r*Ff + d];
  __syncthreads();
  float hv = 0.f;
  #pragma unroll
  for(int f=0; f<Ff; f++) hv += xr[f]*W1[f*Dd + d];
  h[r*Dd + d] = hv;
  float e = emb[node*Dd + d];
  float a = hv*ai1[d] + e*ai1[Dd + d];
  float b = hv*aj1[d] + e*aj1[Dd + d];
  for(int o=32;o>0;o>>=1){ a += __shfl_down(a,o,64); b += __shfl_down(b,o,64); }
  if(d==0){ si[r] = a; sj[r] = b; }
}

// ---------------- layer-1 segment softmax + aggregation ----------------
__global__ void k_agg1(const float* __restrict__ h, const float* __restrict__ si,
                       const float* __restrict__ sj, const float* __restrict__ topv,
                       const int* __restrict__ topi, const float* __restrict__ bias1,
                       float* __restrict__ agg){
  int r = blockIdx.x, d = threadIdx.x;
  int b = r >> 7, node = r & (Nn-1);
  __shared__ float sal[TOPK];
  __shared__ int   ssrc[TOPK];
  if(d < TOPK){
    int s = b*Nn + topi[node*TOPK + d];
    float sc = si[r] + sj[s];
    sc = sc >= 0.f ? sc : SLOPE*sc;
    sal[d] = sc * topv[node*TOPK + d];
    ssrc[d] = s;
  }
  __syncthreads();
  float m = -INFINITY;
  #pragma unroll
  for(int k=0;k<TOPK;k++) m = fmaxf(m, sal[k]);
  float al[TOPK]; float ssum = 0.f;
  #pragma unroll
  for(int k=0;k<TOPK;k++){ al[k] = expf(sal[k]-m); ssum += al[k]; }
  float inv = 1.0f/fmaxf(ssum, 1e-12f);
  float acc = 0.f;
  #pragma unroll
  for(int k=0;k<TOPK;k++) acc += al[k]*inv*h[ssrc[k]*Dd + d];
  agg[r*Dd + d] = acc + bias1[d];
}

// ---------------- per-channel stats over BN rows (agg1) ----------------
__global__ void k_colstats(const float* __restrict__ x, float* __restrict__ mu, float* __restrict__ var){
  int c = blockIdx.x, t = threadIdx.x;
  float s = 0.f, s2 = 0.f;
  for(int r=t; r<BN; r+=256){ float v = x[r*Dd + c]; s += v; s2 += v*v; }
  __shared__ float ls[256], ls2[256];
  ls[t]=s; ls2[t]=s2; __syncthreads();
  for(int o=128;o>0;o>>=1){
    if(t<o){ ls[t]+=ls[t+o]; ls2[t]+=ls2[t+o]; }
    __syncthreads();
  }
  if(t==0){ float m = ls[0]/BN; mu[c]=m; var[c]=ls2[0]/BN - m*m; }
}

// ---------------- BN1 + relu -> g[0:BN] ----------------
__global__ void k_bnrelu1(const float* __restrict__ agg, const float* __restrict__ mu,
                          const float* __restrict__ var, const float* __restrict__ gamma,
                          const float* __restrict__ beta, float* __restrict__ g){
  int idx = blockIdx.x*256 + threadIdx.x;
  int c = idx & (Dd-1);
  float v = agg[idx];
  float y = gamma[c]*(v - mu[c])/sqrtf(var[c]+EPS) + beta[c];
  g[idx] = fmaxf(y, 0.f);
}

// ---------------- ef = P^T @ gcn : float4 staging, grid (64 j-tiles, 16 r-chunks) ----------------
__global__ __launch_bounds__(256) void k_ef(const float* __restrict__ P, const float* __restrict__ gcn,
                                            float* __restrict__ ef){
  __shared__ float Pt[16*64];
  __shared__ float Gt[16*64];
  int t = threadIdx.x;
  int jbase = blockIdx.x*64;
  int r0 = blockIdx.y*256;
  int row = t >> 4, col4 = (t & 15)*4;
  int tr = t >> 4, tc = t & 15;
  float acc[4][4] = {};
  for(int step=0; step<16; step++){
    int r = r0 + step*16;
    float4 pv = *(const float4*)&P[(size_t)(r+row)*BN + jbase + col4];
    float4 gv = *(const float4*)&gcn[(r+row)*Dd + col4];
    __syncthreads();
    *(float4*)&Pt[row*64 + col4] = pv;
    *(float4*)&Gt[row*64 + col4] = gv;
    __syncthreads();
    #pragma unroll
    for(int rr=0; rr<16; rr++){
      float4 pa = *(float4*)&Pt[rr*64 + tr*4];
      float4 gb = *(float4*)&Gt[rr*64 + tc*4];
      float pav[4] = {pa.x, pa.y, pa.z, pa.w};
      float gbv[4] = {gb.x, gb.y, gb.z, gb.w};
      #pragma unroll
      for(int a=0;a<4;a++)
        #pragma unroll
        for(int b=0;b<4;b++) acc[a][b] += pav[a]*gbv[b];
    }
  }
  #pragma unroll
  for(int a=0;a<4;a++)
    #pragma unroll
    for(int b=0;b<4;b++)
      atomicAdd(&ef[(jbase + tr*4 + a)*Dd + tc*4 + b], acc[a][b]);
}

// ---------------- row norms of g (8192 rows) ----------------
__global__ void k_rownorm(const float* __restrict__ x, float* __restrict__ nrm){
  int r = blockIdx.x, d = threadIdx.x;
  float v = x[(size_t)r*Dd + d];
  float s = v*v;
  for(int o=32;o>0;o>>=1) s += __shfl_down(s, o, 64);
  if(d==0) nrm[r] = fmaxf(sqrtf(s), 1e-12f);
}

// ---------------- S chunk GEMM: S[r][c] = cos(g[rbase+r], g[c]) ----------------
// 128x128 tile, 256 threads, 8x8 acc, LDS layout [k][m] (transposed), norm folded into staging.
__global__ __launch_bounds__(256) void k_sgemm(const float* __restrict__ g, const float* __restrict__ gnorm,
                                               int rbase, float* __restrict__ S){
  __shared__ float A[64*128];
  __shared__ float Bs[64*128];
  int t = threadIdx.x;
  int ctile = blockIdx.x*128;
  int rtile = rbase + blockIdx.y*128;
  int q = t >> 4, m0 = t & 15;          // q: k4 group (0..15), m0: row (0..15)
  #pragma unroll
  for(int l=0;l<8;l++){
    int m = m0 + 16*l;
    float ia = 1.0f/gnorm[rtile + m];
    float ib = 1.0f/gnorm[ctile + m];
    float4 av = *(const float4*)&g[(size_t)(rtile+m)*Dd + q*4];
    float4 bv = *(const float4*)&g[(size_t)(ctile+m)*Dd + q*4];
    A[(q*4+0)*128 + m] = av.x*ia; A[(q*4+1)*128 + m] = av.y*ia;
    A[(q*4+2)*128 + m] = av.z*ia; A[(q*4+3)*128 + m] = av.w*ia;
    Bs[(q*4+0)*128 + m] = bv.x*ib; Bs[(q*4+1)*128 + m] = bv.y*ib;
    Bs[(q*4+2)*128 + m] = bv.z*ib; Bs[(q*4+3)*128 + m] = bv.w*ib;
  }
  __syncthreads();
  int tr = t >> 4;   // m-group (broadcast within wave)
  int tc = t & 15;   // n-group (fast index -> semi-coalesced stores)
  float acc[8][8] = {};
  #pragma unroll 4
  for(int k=0;k<64;k++){
    float a[8], b[8];
    #pragma unroll
    for(int i=0;i<8;i++) a[i] = A[k*128 + tr + 16*i];
    #pragma unroll
    for(int j=0;j<8;j++) b[j] = Bs[k*128 + tc + 16*j];
    #pragma unroll
    for(int i=0;i<8;i++)
      #pragma unroll
      for(int j=0;j<8;j++) acc[i][j] += a[i]*b[j];
  }
  int rloc = blockIdx.y*128;
  #pragma unroll
  for(int i=0;i<8;i++){
    int r = rloc + tr + 16*i;
    #pragma unroll
    for(int j=0;j<8;j++)
      S[(size_t)r*TBN + ctile + tc + 16*j] = acc[i][j];
  }
}

// ---------------- top-25 per row: single-wave incremental argmax ----------------
// One 64-lane wave per row; padded LDS (+1 float per 256) kills the 256-stride
// bank aliasing; removal rescan is cooperative (2 elems/lane + butterfly).
__global__ __launch_bounds__(64) void k_top2(const float* __restrict__ S, int rbase,
                                             float* __restrict__ topv2, int* __restrict__ topi2){
  __shared__ float row[TBN + TBN/256];
  int t = threadIdx.x;
  int r = blockIdx.x;
  const float* src = S + (size_t)r*TBN;
  float mv = -INFINITY; int mi = 0x7FFFFFFF;
  #pragma unroll
  for(int i=0;i<32;i++){
    int c = i*256 + t*4;
    float4 v = *(const float4*)&src[c];
    int p = c + (c>>8);
    row[p] = v.x; row[p+1] = v.y; row[p+2] = v.z; row[p+3] = v.w;
    if(v.x > mv){mv=v.x;mi=c;}
    if(v.y > mv){mv=v.y;mi=c+1;}
    if(v.z > mv){mv=v.z;mi=c+2;}
    if(v.w > mv){mv=v.w;mi=c+3;}
  }
  __syncthreads();
  int gr = rbase + r;
  for(int k=0;k<EXTRA;k++){
    // global argmax via butterfly (all lanes converge)
    float gv = mv; int gi = mi;
    #pragma unroll
    for(int o=1;o<64;o<<=1){
      float v2 = __shfl_xor(gv,o,64); int i2 = __shfl_xor(gi,o,64);
      if(v2 > gv || (v2 == gv && i2 < gi)){ gv=v2; gi=i2; }
    }
    if(t==0){ topv2[gr*EXTRA+k]=gv; topi2[gr*EXTRA+k]=gi; }
    int owner = (gi >> 2) & 63;
    if(t == owner) row[gi + (gi>>8)] = -INFINITY;
    __syncthreads();   // single-wave barrier: orders the LDS write
    // cooperative rescan of owner's 128-element segment: 2 elems/lane
    int c = (t>>1)*256 + owner*4 + (t&1)*2;
    int p = c + (c>>8);
    float a = row[p], b = row[p+1];
    float nv; int ni;
    if(a >= b){ nv=a; ni=c; } else { nv=b; ni=c+1; }
    #pragma unroll
    for(int o=1;o<64;o<<=1){
      float v2 = __shfl_xor(nv,o,64); int i2 = __shfl_xor(ni,o,64);
      if(v2 > nv || (v2 == nv && i2 < ni)){ nv=v2; ni=i2; }
    }
    if(t == owner){ mv = nv; mi = ni; }
  }
}

// ---------------- h2 = g@W2, attention logits ----------------
__global__ void k_h2(const float* __restrict__ g, const float* __restrict__ W2,
                     const float* __restrict__ ai2w, const float* __restrict__ aj2w,
                     float* __restrict__ h2, float* __restrict__ a2i, float* __restrict__ a2j){
  int r = blockIdx.x, d = threadIdx.x;
  __shared__ float gr[Dd];
  gr[d] = g[(size_t)r*Dd + d];
  __syncthreads();
  float hv = 0.f;
  #pragma unroll
  for(int k=0;k<Dd;k++) hv += gr[k]*W2[k*Dd + d];
  h2[(size_t)r*Dd + d] = hv;
  float a = hv*ai2w[d];
  float b = hv*aj2w[d];
  for(int o=32;o>0;o>>=1){ a += __shfl_down(a,o,64); b += __shfl_down(b,o,64); }
  if(d==0){ a2i[r]=a; a2j[r]=b; }
}

// ---------------- layer-2 edge scores + segment max ----------------
__global__ void k_s2(const float* __restrict__ a2i, const float* __restrict__ a2j,
                     const float* __restrict__ topv2, const int* __restrict__ topi2,
                     float* __restrict__ s2, unsigned int* __restrict__ segmax){
  int e = blockIdx.x*256 + threadIdx.x;
  if(e >= BN*EXTRA) return;
  int r = e/EXTRA;
  int dst = topi2[e];
  float sc = a2i[dst] + a2j[r];
  sc = sc >= 0.f ? sc : SLOPE*sc;
  sc *= topv2[e];
  s2[e] = sc;
  atomicMax(&segmax[dst], fenc(sc));
}

// ---------------- exp + segment sum ----------------
__global__ void k_e2(const float* __restrict__ s2, const int* __restrict__ topi2,
                     const unsigned int* __restrict__ segmax,
                     float* __restrict__ e2, float* __restrict__ ssum){
  int e = blockIdx.x*256 + threadIdx.x;
  if(e >= BN*EXTRA) return;
  int dst = topi2[e];
  float m = fdec(segmax[dst]);
  float v = expf(s2[e] - m);
  e2[e] = v;
  atomicAdd(&ssum[dst], v);
}

// ---------------- weighted scatter into agg2 ----------------
__global__ void k_scat(const float* __restrict__ e2, const float* __restrict__ ssum,
                       const int* __restrict__ topi2, const float* __restrict__ h2,
                       float* __restrict__ agg2){
  int idx = blockIdx.x*256 + threadIdx.x;
  int e = idx >> 6, d = idx & 63;
  int dst = topi2[e];
  int src = e/EXTRA;
  float alpha = e2[e]/fmaxf(ssum[dst], 1e-12f);
  atomicAdd(&agg2[(size_t)dst*Dd + d], alpha*h2[(size_t)src*Dd + d]);
}

// ---------------- head stats over x3 = relu(agg2+bias2)*emb ----------------
__global__ void k_headstats(const float* __restrict__ agg2, const float* __restrict__ bias2,
                            const float* __restrict__ emb, float* __restrict__ mu2, float* __restrict__ var2){
  int c = blockIdx.x, t = threadIdx.x;
  float bc = bias2[c];
  float s = 0.f, s2 = 0.f;
  for(int r=t; r<BN; r+=256){
    float v = fmaxf(agg2[(size_t)r*Dd + c] + bc, 0.f) * emb[(r & (Nn-1))*Dd + c];
    s += v; s2 += v*v;
  }
  __shared__ float ls[256], ls2[256];
  ls[t]=s; ls2[t]=s2; __syncthreads();
  for(int o=128;o>0;o>>=1){
    if(t<o){ ls[t]+=ls[t+o]; ls2[t]+=ls2[t+o]; }
    __syncthreads();
  }
  if(t==0){ float m=ls[0]/BN; mu2[c]=m; var2[c]=ls2[0]/BN - m*m; }
}

// ---------------- final: BN + relu + Linear(D,1) ----------------
__global__ void k_out(const float* __restrict__ agg2, const float* __restrict__ bias2,
                      const float* __restrict__ emb, const float* __restrict__ mu2,
                      const float* __restrict__ var2, const float* __restrict__ gO,
                      const float* __restrict__ bO, const float* __restrict__ Wout,
                      const float* __restrict__ bout, float* __restrict__ out){
  int r = blockIdx.x, d = threadIdx.x;
  float v = fmaxf(agg2[(size_t)r*Dd + d] + bias2[d], 0.f) * emb[(r & (Nn-1))*Dd + d];
  float y = gO[d]*(v - mu2[d])/sqrtf(var2[d]+EPS) + bO[d];
  y = fmaxf(y, 0.f)*Wout[d];
  for(int o=32;o>0;o>>=1) y += __shfl_down(y, o, 64);
  if(d==0) out[r] = y + bout[0];
}

extern "C" void kernel_launch(void* const* d_in, const int* in_sizes, int n_in,
                              void* d_out, int out_size, void* d_ws, size_t ws_size,
                              hipStream_t stream){
  const float* data  = (const float*)d_in[0];
  const float* emb   = (const float*)d_in[1];
  const float* W1    = (const float*)d_in[2];
  const float* ai1   = (const float*)d_in[3];
  const float* aj1   = (const float*)d_in[4];
  const float* bias1 = (const float*)d_in[5];
  const float* bn1g  = (const float*)d_in[6];
  const float* bn1b  = (const float*)d_in[7];
  const float* P     = (const float*)d_in[8];
  const float* W2    = (const float*)d_in[9];
  const float* ai2w  = (const float*)d_in[10];
  const float* aj2w  = (const float*)d_in[11];
  const float* bias2 = (const float*)d_in[12];
  const float* bnOg  = (const float*)d_in[13];
  const float* bnOb  = (const float*)d_in[14];
  const float* Wout  = (const float*)d_in[15];
  const float* bout  = (const float*)d_in[16];
  float* out = (float*)d_out;

  char* w = (char*)d_ws;
  auto alloc = [&](size_t nbytes)->char*{
    char* p = w; w += (nbytes + 255) & ~(size_t)255; return p;
  };
  float* norms1 = (float*)alloc(Nn*4);
  float* topv1  = (float*)alloc(Nn*TOPK*4);
  int*   topi1  = (int*)  alloc(Nn*TOPK*4);
  float* h      = (float*)alloc((size_t)BN*Dd*4);
  float* si     = (float*)alloc(BN*4);
  float* sj     = (float*)alloc(BN*4);
  float* agg1   = (float*)alloc((size_t)BN*Dd*4);
  float* mu1    = (float*)alloc(Dd*4);
  float* var1   = (float*)alloc(Dd*4);
  float* g      = (float*)alloc((size_t)TBN*Dd*4);
  float* gnorm  = (float*)alloc(TBN*4);
  float* topv2  = (float*)alloc((size_t)BN*EXTRA*4);
  int*   topi2  = (int*)  alloc((size_t)BN*EXTRA*4);
  float* h2     = (float*)alloc((size_t)TBN*Dd*4);
  float* a2i    = (float*)alloc(TBN*4);
  float* a2j    = (float*)alloc(TBN*4);
  float* s2     = (float*)alloc((size_t)BN*EXTRA*4);
  float* e2     = (float*)alloc((size_t)BN*EXTRA*4);
  // contiguous zero region: agg2 | ssum | segmax
  float* zblock = (float*)alloc(((size_t)TBN*Dd + TBN + TBN)*4);
  float* agg2   = zblock;
  float* ssum   = zblock + (size_t)TBN*Dd;
  unsigned int* segmax = (unsigned int*)(ssum + TBN);
  float* mu2    = (float*)alloc(Dd*4);
  float* var2   = (float*)alloc(Dd*4);

  // adaptive S-chunk (multiple of 128 rows; prefer one big chunk)
  size_t used = (size_t)(w - (char*)d_ws);
  size_t rem  = ws_size > used ? ws_size - used : 0;
  int chunkRows = 4096;
  while(chunkRows > 128 && (size_t)chunkRows*TBN*4 > rem) chunkRows >>= 1;
  float* Schunk = (float*)alloc((size_t)chunkRows*TBN*4);

  // ---- layer 1 ----
  k_emb_norm<<<Nn, 64, 0, stream>>>(emb, norms1);
  k_emb_topk<<<Nn, Nn, 0, stream>>>(emb, norms1, topv1, topi1);
  k_h1<<<BN, 64, 0, stream>>>(data, emb, W1, ai1, aj1, h, si, sj);
  k_agg1<<<BN, 64, 0, stream>>>(h, si, sj, topv1, topi1, bias1, agg1);
  k_colstats<<<Dd, 256, 0, stream>>>(agg1, mu1, var1);
  k_bnrelu1<<<(BN*Dd)/256, 256, 0, stream>>>(agg1, mu1, var1, bn1g, bn1b, g);

  // ---- ef = P^T gcn ----
  k_zero<<<(BN*Dd)/256, 256, 0, stream>>>(g + (size_t)BN*Dd, BN*Dd);
  k_ef<<<dim3(64, 16), 256, 0, stream>>>(P, g, g + (size_t)BN*Dd);

  // ---- cos2 top-25 (chunked; only first BN rows consumed downstream) ----
  k_rownorm<<<TBN, 64, 0, stream>>>(g, gnorm);
  for(int rbase=0; rbase<BN; rbase+=chunkRows){
    k_sgemm<<<dim3(TBN/128, chunkRows/128), 256, 0, stream>>>(g, gnorm, rbase, Schunk);
    k_top2<<<chunkRows, 64, 0, stream>>>(Schunk, rbase, topv2, topi2);
  }

  // ---- layer 2 ----
  k_h2<<<TBN, 64, 0, stream>>>(g, W2, ai2w, aj2w, h2, a2i, a2j);
  k_zero<<<((TBN*Dd + 2*TBN) + 255)/256, 256, 0, stream>>>(zblock, TBN*Dd + 2*TBN);
  k_s2<<<(BN*EXTRA + 255)/256, 256, 0, stream>>>(a2i, a2j, topv2, topi2, s2, segmax);
  k_e2<<<(BN*EXTRA + 255)/256, 256, 0, stream>>>(s2, topi2, segmax, e2, ssum);
  k_scat<<<(BN*EXTRA*Dd)/256, 256, 0, stream>>>(e2, ssum, topi2, h2, agg2);

  // ---- head ----
  k_headstats<<<Dd, 256, 0, stream>>>(agg2, bias2, emb, mu2, var2);
  k_out<<<BN, 64, 0, stream>>>(agg2, bias2, emb, mu2, var2, bnOg, bnOb, Wout, bout, out);
}